// Round 4
// baseline (18708.742 us; speedup 1.0000x reference)
//
#include <hip/hip_runtime.h>
#include <hip/hip_bf16.h>
#include <stdint.h>

#define TT 2048
#define BB 32
#define II 256
#define HH 256
#define NG 16          // workgroups
#define HW 16          // h-dims per workgroup (HH/NG)
#define LROW 264       // h_lds row stride in shorts (528B: 16B-aligned, 2-way banks = free)

typedef __attribute__((ext_vector_type(8))) short short8;
typedef __attribute__((ext_vector_type(4))) float floatx4;

__device__ __forceinline__ short bf16r(float f) {
    __hip_bfloat16 b = __float2bfloat16(f);
    return *reinterpret_cast<short*>(&b);
}

// 16 WGs x 256 threads, weights register-stationary (1 MB chip-wide).
// h exchange: tagged dwords {t<<16 | bf16(h)} in d_ws, double-buffered by
// t&1, relaxed agent atomics (sc1 = LLC-direct) — data IS the flag; no
// fences, no wbl2/inv, no ordering ops. ys/out is fire-and-forget fp32.
__global__ __launch_bounds__(256, 1)
void rev_lstm_kernel(const float* __restrict__ x,
                     const float* __restrict__ h0,
                     const float* __restrict__ c0,
                     const float* __restrict__ Wih,
                     const float* __restrict__ Whh,
                     const float* __restrict__ bih,
                     const float* __restrict__ bhh,
                     float* __restrict__ out,
                     unsigned int* __restrict__ xch)
{
    __shared__ short h_lds[BB * LROW];
    __shared__ float gates_lds[4 * BB * HW];   // [gate][b][j]

    const int w    = blockIdx.x;      // 0..15
    const int tid  = threadIdx.x;     // 0..255
    const int wid  = tid >> 6;        // wave id == gate id (i,f,g,o)
    const int lane = tid & 63;
    const int l15  = lane & 15;
    const int quad = lane >> 4;       // 0..3

    // ---- stationary weight B-fragments (B[k][n]: n=lane&15 -> col, k=quad*8+j)
    const int col = wid * HH + w * HW + l15;          // gate column in [0,1024)
    short8 wihf[8], whhf[8];
#pragma unroll
    for (int kt = 0; kt < 8; ++kt) {
        const int k0 = kt * 32 + quad * 8;
        const float* pi = Wih + (size_t)col * II + k0;
        const float* ph = Whh + (size_t)col * HH + k0;
        short8 a, b;
#pragma unroll
        for (int j = 0; j < 8; ++j) { a[j] = bf16r(pi[j]); b[j] = bf16r(ph[j]); }
        wihf[kt] = a; whhf[kt] = b;
    }
    const float bias = bih[col] + bhh[col];

    // ---- c state fp32 in registers; thread owns (b=jb, j=jj) and (b=jb+16, j=jj)
    const int jb = tid >> 4;   // 0..15
    const int jj = tid & 15;   // 0..15
    float creg0 = c0[(size_t)jb * HH + w * HW + jj];
    float creg1 = c0[(size_t)(jb + 16) * HH + w * HW + jj];

    // ---- prefill h_lds with h0 (fp32 -> bf16)
    const int pb = tid >> 3, pseg = tid & 7;          // poll/gather mapping
    {
        const float* src = h0 + (size_t)pb * HH + pseg * 32;
#pragma unroll
        for (int u = 0; u < 32; ++u) h_lds[pb * LROW + pseg * 32 + u] = bf16r(src[u]);
    }
    __syncthreads();

    for (int t = TT - 1; t >= 0; --t) {
        // ---- 1. x-part: loads + cvt + x-MFMAs (h-independent, overlaps the wait)
        floatx4 acc0 = {bias, bias, bias, bias};
        floatx4 acc1 = {bias, bias, bias, bias};
        const float* xt = x + (size_t)t * (BB * II);
#pragma unroll
        for (int kt = 0; kt < 8; ++kt) {
            const int k0 = kt * 32 + quad * 8;
            const float4 u0 = *reinterpret_cast<const float4*>(xt + (size_t)l15 * II + k0);
            const float4 u1 = *reinterpret_cast<const float4*>(xt + (size_t)l15 * II + k0 + 4);
            const float4 v0 = *reinterpret_cast<const float4*>(xt + (size_t)(l15 + 16) * II + k0);
            const float4 v1 = *reinterpret_cast<const float4*>(xt + (size_t)(l15 + 16) * II + k0 + 4);
            short8 a, b;
            a[0]=bf16r(u0.x); a[1]=bf16r(u0.y); a[2]=bf16r(u0.z); a[3]=bf16r(u0.w);
            a[4]=bf16r(u1.x); a[5]=bf16r(u1.y); a[6]=bf16r(u1.z); a[7]=bf16r(u1.w);
            b[0]=bf16r(v0.x); b[1]=bf16r(v0.y); b[2]=bf16r(v0.z); b[3]=bf16r(v0.w);
            b[4]=bf16r(v1.x); b[5]=bf16r(v1.y); b[6]=bf16r(v1.z); b[7]=bf16r(v1.w);
            acc0 = __builtin_amdgcn_mfma_f32_16x16x32_bf16(a, wihf[kt], acc0, 0, 0, 0);
            acc1 = __builtin_amdgcn_mfma_f32_16x16x32_bf16(b, wihf[kt], acc1, 0, 0, 0);
        }

        // ---- 2. poll tagged h_{t+1} dwords straight from LLC; data IS the flag
        if (t != TT - 1) {
            const unsigned want = ((unsigned)(t + 1)) << 16;
            const unsigned* base = xch + (((unsigned)(t + 1)) & 1u) * (BB * HH)
                                       + pb * HH + pseg * 32;
            unsigned v[32];
            int rounds = 0;
            bool ok;
            do {
#pragma unroll
                for (int i = 0; i < 32; ++i)
                    v[i] = __hip_atomic_load(base + i, __ATOMIC_RELAXED,
                                             __HIP_MEMORY_SCOPE_AGENT);
                ok = true;
#pragma unroll
                for (int i = 0; i < 32; ++i)
                    ok = ok && ((v[i] & 0xFFFF0000u) == want);
            } while (!ok && ++rounds < 5000);   // fail loud, never hang

            // bf16 payloads -> LDS (packed pairs, 4x b128 writes)
#pragma unroll
            for (int q = 0; q < 4; ++q) {
                uint4 d;
                d.x = (v[q*8+0] & 0xFFFFu) | (v[q*8+1] << 16);
                d.y = (v[q*8+2] & 0xFFFFu) | (v[q*8+3] << 16);
                d.z = (v[q*8+4] & 0xFFFFu) | (v[q*8+5] << 16);
                d.w = (v[q*8+6] & 0xFFFFu) | (v[q*8+7] << 16);
                *reinterpret_cast<uint4*>(h_lds + pb * LROW + pseg * 32 + q * 8) = d;
            }
            __syncthreads();
        }

        // ---- 3. recurrent MFMAs: += h@Whh^T
#pragma unroll
        for (int kt = 0; kt < 8; ++kt) {
            const int off = kt * 32 + quad * 8;
            short8 ha0 = *reinterpret_cast<const short8*>(h_lds + l15 * LROW + off);
            short8 ha1 = *reinterpret_cast<const short8*>(h_lds + (l15 + 16) * LROW + off);
            acc0 = __builtin_amdgcn_mfma_f32_16x16x32_bf16(ha0, whhf[kt], acc0, 0, 0, 0);
            acc1 = __builtin_amdgcn_mfma_f32_16x16x32_bf16(ha1, whhf[kt], acc1, 0, 0, 0);
        }

        // ---- 4. accumulators -> LDS (C/D layout: col=lane&15, row=quad*4+r)
#pragma unroll
        for (int r = 0; r < 4; ++r) {
            gates_lds[(wid * BB + quad * 4 + r) * HW + l15]      = acc0[r];
            gates_lds[(wid * BB + 16 + quad * 4 + r) * HW + l15] = acc1[r];
        }
        __syncthreads();

        // ---- 5. elementwise cell; tagged h -> exchange (critical), ys -> out (lazy)
#pragma unroll
        for (int n = 0; n < 2; ++n) {
            const int b = jb + n * 16;
            const float ig = gates_lds[(0 * BB + b) * HW + jj];
            const float fg = gates_lds[(1 * BB + b) * HW + jj];
            const float gg = gates_lds[(2 * BB + b) * HW + jj];
            const float og = gates_lds[(3 * BB + b) * HW + jj];
            const float is = 1.f / (1.f + __expf(-ig));
            const float fs = 1.f / (1.f + __expf(-fg));
            const float gt = 1.f - 2.f / (1.f + __expf(2.f * gg));
            const float os = 1.f / (1.f + __expf(-og));
            const float cprev = (n == 0) ? creg0 : creg1;
            const float c  = fs * cprev + is * gt;
            const float h  = os * (1.f - 2.f / (1.f + __expf(2.f * c)));
            if (n == 0) creg0 = c; else creg1 = c;

            const unsigned pack = (((unsigned)t) << 16)
                                | (unsigned)(unsigned short)bf16r(h);
            __hip_atomic_store(xch + ((unsigned)t & 1u) * (BB * HH)
                                   + (size_t)b * HH + w * HW + jj,
                               pack, __ATOMIC_RELAXED, __HIP_MEMORY_SCOPE_AGENT);

            out[(size_t)t * (BB * HH) + (size_t)b * HH + w * HW + jj] = h;
            if (t == 0) {
                out[(size_t)TT * (BB * HH) + (size_t)b * HH + w * HW + jj] = h;
                out[(size_t)TT * (BB * HH) + (BB * HH) + (size_t)b * HH + w * HW + jj] = c;
            }
        }
        // no trailing barrier needed: next iteration's LDS writes are fenced by
        // its own post-gather barrier, and gates_lds reads complete before any
        // thread can pass that barrier.
    }
}

extern "C" void kernel_launch(void* const* d_in, const int* in_sizes, int n_in,
                              void* d_out, int out_size, void* d_ws, size_t ws_size,
                              hipStream_t stream) {
    const float* x   = (const float*)d_in[0];
    const float* h0  = (const float*)d_in[1];
    const float* c0  = (const float*)d_in[2];
    const float* Wih = (const float*)d_in[3];
    const float* Whh = (const float*)d_in[4];
    const float* bih = (const float*)d_in[5];
    const float* bhh = (const float*)d_in[6];
    float* out = (float*)d_out;
    unsigned int* xch = (unsigned int*)d_ws;   // 2 * 32*256 * 4B = 64 KB

    // tag bytes 0xAAAA never match any step tag (< 2048); memset guards the
    // first (correctness) call in case d_ws arrives un-poisoned.
    hipMemsetAsync(xch, 0xAA, 2 * BB * HH * sizeof(unsigned int), stream);
    hipLaunchKernelGGL(rev_lstm_kernel, dim3(NG), dim3(256), 0, stream,
                       x, h0, c0, Wih, Whh, bih, bhh, out, xch);
}

// Round 5
// 13336.742 us; speedup vs baseline: 1.4028x; 1.4028x over previous
//
#include <hip/hip_runtime.h>
#include <hip/hip_bf16.h>
#include <stdint.h>

#define TT 2048
#define BB 32
#define II 256
#define HH 256
#define NP 16          // participating workgroups (all on ONE XCD)
#define HW 16          // h-dims per participant (HH/NP)
#define LROW 264       // h_lds row stride in shorts (528B: 16B-aligned, 2-way banks free)

typedef __attribute__((ext_vector_type(8))) short short8;
typedef __attribute__((ext_vector_type(4))) float floatx4;

__device__ __forceinline__ short bf16r(float f) {
    __hip_bfloat16 b = __float2bfloat16(f);
    return *reinterpret_cast<short*>(&b);
}

// L2-coherent (same-XCD) ops: sc0 = L1 bypass; CDNA L1 is write-through so
// stores land in the shared XCD L2, loads with sc0 read it coherently.
__device__ __forceinline__ void st_sc0(unsigned* p, unsigned v) {
    asm volatile("global_store_dword %0, %1, off sc0" :: "v"(p), "v"(v) : "memory");
}
__device__ __forceinline__ uint4 ld4_sc0(const unsigned* p) {
    uint4 r;
    asm volatile("global_load_dwordx4 %0, %1, off sc0" : "=v"(r) : "v"(p) : "memory");
    return r;
}
__device__ __forceinline__ void waitvm0() {
    asm volatile("s_waitcnt vmcnt(0)" ::: "memory");
}

// 256 WGs launched; 16 workers elected on one XCD (XCC_ID + CAS leader +
// ticket). Worker w owns h-dims [w*16,w*16+16) -> gate cols {g*256+w*16+j}.
// Weights register-stationary. h exchange: fused {t<<16|bf16(h)} dwords,
// double-buffered by t&1, through the shared XCD L2 via sc0 — data IS the
// flag; no fences. ys -> out via nontemporal stores (keep L2 clean).
__global__ __launch_bounds__(256, 1)
void rev_lstm_kernel(const float* __restrict__ x,
                     const float* __restrict__ h0,
                     const float* __restrict__ c0,
                     const float* __restrict__ Wih,
                     const float* __restrict__ Whh,
                     const float* __restrict__ bih,
                     const float* __restrict__ bhh,
                     float* __restrict__ out,
                     unsigned int* __restrict__ ws)
{
    unsigned* ctr = ws;                 // [0]=leader CAS (xcc+1), [1]=ticket
    unsigned* xch = ws + 16;            // 2 * BB*HH tagged dwords (64 KB)

    __shared__ int s_w;
    __shared__ short h_lds[BB * LROW];
    __shared__ float gates_lds[4 * BB * HW];   // [gate][b][j]

    const int tid = threadIdx.x;

    // ---- election: first-arriving XCD wins; its first 16 WGs participate
    if (tid == 0) {
        const unsigned xcc = __builtin_amdgcn_s_getreg(63508) & 0xFu; // HW_REG_XCC_ID
        const unsigned old = atomicCAS(ctr, 0u, xcc + 1u);
        const unsigned chosen = (old == 0u) ? (xcc + 1u) : old;
        int w = -1;
        if (xcc + 1u == chosen) {
            const unsigned r = atomicAdd(ctr + 1, 1u);
            if (r < NP) w = (int)r;
        }
        s_w = w;
    }
    __syncthreads();
    const int w = s_w;
    if (w < 0) return;                  // non-participant

    const int wid  = tid >> 6;          // wave id == gate id (i,f,g,o)
    const int lane = tid & 63;
    const int l15  = lane & 15;
    const int quad = lane >> 4;

    // ---- stationary weight B-fragments (B[k][n]: n=lane&15 -> col, k=quad*8+j)
    const int col = wid * HH + w * HW + l15;
    short8 wihf[8], whhf[8];
#pragma unroll
    for (int kt = 0; kt < 8; ++kt) {
        const int k0 = kt * 32 + quad * 8;
        const float* pi = Wih + (size_t)col * II + k0;
        const float* ph = Whh + (size_t)col * HH + k0;
        short8 a, b;
#pragma unroll
        for (int j = 0; j < 8; ++j) { a[j] = bf16r(pi[j]); b[j] = bf16r(ph[j]); }
        wihf[kt] = a; whhf[kt] = b;
    }
    const float bias = bih[col] + bhh[col];

    // ---- c state fp32; thread owns (b=jb, j=jj) and (b=jb+16, j=jj)
    const int jb = tid >> 4;
    const int jj = tid & 15;
    float creg0 = c0[(size_t)jb * HH + w * HW + jj];
    float creg1 = c0[(size_t)(jb + 16) * HH + w * HW + jj];

    // ---- prefill h_lds with h0 (fp32 -> bf16)
    const int pb = tid >> 3, pseg = tid & 7;     // poll/gather mapping
    {
        const float* src = h0 + (size_t)pb * HH + pseg * 32;
#pragma unroll
        for (int u = 0; u < 32; ++u) h_lds[pb * LROW + pseg * 32 + u] = bf16r(src[u]);
    }
    __syncthreads();

    for (int t = TT - 1; t >= 0; --t) {
        // ---- 1. x-part (h-independent): loads + cvt + x-MFMAs overlap the wait
        floatx4 acc0 = {bias, bias, bias, bias};
        floatx4 acc1 = {bias, bias, bias, bias};
        const float* xt = x + (size_t)t * (BB * II);
#pragma unroll
        for (int kt = 0; kt < 8; ++kt) {
            const int k0 = kt * 32 + quad * 8;
            const float4 u0 = *reinterpret_cast<const float4*>(xt + (size_t)l15 * II + k0);
            const float4 u1 = *reinterpret_cast<const float4*>(xt + (size_t)l15 * II + k0 + 4);
            const float4 v0 = *reinterpret_cast<const float4*>(xt + (size_t)(l15 + 16) * II + k0);
            const float4 v1 = *reinterpret_cast<const float4*>(xt + (size_t)(l15 + 16) * II + k0 + 4);
            short8 a, b;
            a[0]=bf16r(u0.x); a[1]=bf16r(u0.y); a[2]=bf16r(u0.z); a[3]=bf16r(u0.w);
            a[4]=bf16r(u1.x); a[5]=bf16r(u1.y); a[6]=bf16r(u1.z); a[7]=bf16r(u1.w);
            b[0]=bf16r(v0.x); b[1]=bf16r(v0.y); b[2]=bf16r(v0.z); b[3]=bf16r(v0.w);
            b[4]=bf16r(v1.x); b[5]=bf16r(v1.y); b[6]=bf16r(v1.z); b[7]=bf16r(v1.w);
            acc0 = __builtin_amdgcn_mfma_f32_16x16x32_bf16(a, wihf[kt], acc0, 0, 0, 0);
            acc1 = __builtin_amdgcn_mfma_f32_16x16x32_bf16(b, wihf[kt], acc1, 0, 0, 0);
        }

        // ---- 2. poll tagged h_{t+1} from the shared XCD L2 (sc0); data IS the flag
        if (t != TT - 1) {
            const unsigned want = ((unsigned)(t + 1)) << 16;
            const unsigned* base = xch + (((unsigned)(t + 1)) & 1u) * (BB * HH)
                                       + pb * HH + pseg * 32;
            unsigned v[32];
            int rounds = 0;
            bool ok;
            do {
                uint4 q[8];
#pragma unroll
                for (int i = 0; i < 8; ++i) q[i] = ld4_sc0(base + i * 4);
                waitvm0();
#pragma unroll
                for (int i = 0; i < 8; ++i) {
                    v[i*4+0] = q[i].x; v[i*4+1] = q[i].y;
                    v[i*4+2] = q[i].z; v[i*4+3] = q[i].w;
                }
                ok = true;
#pragma unroll
                for (int i = 0; i < 32; ++i)
                    ok = ok && ((v[i] & 0xFFFF0000u) == want);
            } while (!ok && ++rounds < 1000);   // fail loud, never hang

            // bf16 payloads -> LDS (packed pairs, 4x b128 writes)
#pragma unroll
            for (int q2 = 0; q2 < 4; ++q2) {
                uint4 d;
                d.x = (v[q2*8+0] & 0xFFFFu) | (v[q2*8+1] << 16);
                d.y = (v[q2*8+2] & 0xFFFFu) | (v[q2*8+3] << 16);
                d.z = (v[q2*8+4] & 0xFFFFu) | (v[q2*8+5] << 16);
                d.w = (v[q2*8+6] & 0xFFFFu) | (v[q2*8+7] << 16);
                *reinterpret_cast<uint4*>(h_lds + pb * LROW + pseg * 32 + q2 * 8) = d;
            }
            __syncthreads();
        }

        // ---- 3. recurrent MFMAs: += h@Whh^T
#pragma unroll
        for (int kt = 0; kt < 8; ++kt) {
            const int off = kt * 32 + quad * 8;
            short8 ha0 = *reinterpret_cast<const short8*>(h_lds + l15 * LROW + off);
            short8 ha1 = *reinterpret_cast<const short8*>(h_lds + (l15 + 16) * LROW + off);
            acc0 = __builtin_amdgcn_mfma_f32_16x16x32_bf16(ha0, whhf[kt], acc0, 0, 0, 0);
            acc1 = __builtin_amdgcn_mfma_f32_16x16x32_bf16(ha1, whhf[kt], acc1, 0, 0, 0);
        }

        // ---- 4. accumulators -> LDS (C/D layout: col=lane&15, row=quad*4+r)
#pragma unroll
        for (int r = 0; r < 4; ++r) {
            gates_lds[(wid * BB + quad * 4 + r) * HW + l15]      = acc0[r];
            gates_lds[(wid * BB + 16 + quad * 4 + r) * HW + l15] = acc1[r];
        }
        __syncthreads();

        // ---- 5. cell; tagged h -> L2 exchange (critical), ys -> out (nontemporal)
#pragma unroll
        for (int n = 0; n < 2; ++n) {
            const int b = jb + n * 16;
            const float ig = gates_lds[(0 * BB + b) * HW + jj];
            const float fg = gates_lds[(1 * BB + b) * HW + jj];
            const float gg = gates_lds[(2 * BB + b) * HW + jj];
            const float og = gates_lds[(3 * BB + b) * HW + jj];
            const float is = 1.f / (1.f + __expf(-ig));
            const float fs = 1.f / (1.f + __expf(-fg));
            const float gt = 1.f - 2.f / (1.f + __expf(2.f * gg));
            const float os = 1.f / (1.f + __expf(-og));
            const float cprev = (n == 0) ? creg0 : creg1;
            const float c  = fs * cprev + is * gt;
            const float h  = os * (1.f - 2.f / (1.f + __expf(2.f * c)));
            if (n == 0) creg0 = c; else creg1 = c;

            const unsigned pack = (((unsigned)t) << 16)
                                | (unsigned)(unsigned short)bf16r(h);
            st_sc0(xch + ((unsigned)t & 1u) * (BB * HH) + (size_t)b * HH + w * HW + jj,
                   pack);

            __builtin_nontemporal_store(h, out + (size_t)t * (BB * HH)
                                             + (size_t)b * HH + w * HW + jj);
            if (t == 0) {
                out[(size_t)TT * (BB * HH) + (size_t)b * HH + w * HW + jj] = h;
                out[(size_t)TT * (BB * HH) + (BB * HH) + (size_t)b * HH + w * HW + jj] = c;
            }
        }
        // no trailing barrier: next iteration's LDS writes are fenced by its own
        // post-gather barrier; gates_lds reads complete before anyone passes it.
    }
}

extern "C" void kernel_launch(void* const* d_in, const int* in_sizes, int n_in,
                              void* d_out, int out_size, void* d_ws, size_t ws_size,
                              hipStream_t stream) {
    const float* x   = (const float*)d_in[0];
    const float* h0  = (const float*)d_in[1];
    const float* c0  = (const float*)d_in[2];
    const float* Wih = (const float*)d_in[3];
    const float* Whh = (const float*)d_in[4];
    const float* bih = (const float*)d_in[5];
    const float* bhh = (const float*)d_in[6];
    float* out = (float*)d_out;
    unsigned int* ws = (unsigned int*)d_ws;

    // ctr (election) must start 0; xch tag bytes 0xAAAA never match a step tag.
    hipMemsetAsync(ws, 0, 64, stream);
    hipMemsetAsync(ws + 16, 0xAA, 2 * BB * HH * sizeof(unsigned int), stream);
    hipLaunchKernelGGL(rev_lstm_kernel, dim3(256), dim3(256), 0, stream,
                       x, h0, c0, Wih, Whh, bih, bhh, out, ws);
}